// Round 7
// baseline (114.693 us; speedup 1.0000x reference)
//
#include <hip/hip_runtime.h>
#include <math.h>

typedef __attribute__((ext_vector_type(8))) short short8;
typedef __attribute__((ext_vector_type(4))) float f32x4;

#define SCALE 0.08838834764831845f   // 1/sqrt(128)

// ws byte offsets (total 49408)
#define WS_W1H 0
#define WS_W1L 8192
#define WS_W2H 16384
#define WS_W2L 24576
#define WS_GH  32768
#define WS_GL  40960
#define WS_g   49152

// LDS: Zk hi 8K + lo 8K | 4 x 4K per-wave X/H plane | ck 256B  = 33024 B
#define L_ZK 0
#define L_XH 16384
#define L_CK 32768
#define LDS_BYTES 33024

__device__ __forceinline__ unsigned f2bf(float f) {   // RNE
    unsigned u = __float_as_uint(f);
    return (u + 0x7fffu + ((u >> 16) & 1u)) >> 16;
}
__device__ __forceinline__ float bfhi(unsigned h) { return __uint_as_float(h << 16); }
__device__ __forceinline__ f32x4 mk4(float v) { f32x4 r = {v, v, v, v}; return r; }
// interleaved word: (lo16 << 16) | hi16, trunc split
__device__ __forceinline__ unsigned packHL(float v) {
    unsigned u = __float_as_uint(v);
    float res = v - __uint_as_float(u & 0xffff0000u);
    return (__float_as_uint(res) & 0xffff0000u) | (u >> 16);
}
union U4S8 { uint4 u4; unsigned u[4]; short8 s; };

#define RELU4(ACC) do {                                                  \
    _Pragma("unroll")                                                    \
    for (int _n = 0; _n < 4; ++_n) {                                     \
        _Pragma("unroll")                                                \
        for (int _r = 0; _r < 4; ++_r)                                   \
            (ACC)[_n][_r] = fmaxf((ACC)[_n][_r], 0.f);                   \
    }                                                                    \
} while (0)

// ---- per-quarter PE (R6-proven) + bias feature 42 = 1.0 ----
__device__ __forceinline__ void pe_values(float* v, const float* __restrict__ pose, int qt) {
    float2 r0 = *(const float2*)(pose + 2);
    float2 r1 = *(const float2*)(pose + 6);
    float2 r2 = *(const float2*)(pose + 10);
    const float L[3] = {r0.y, r1.y, r2.y};
    const float sc = (qt == 0) ? 1.5f : ((qt == 1) ? 6.f : 24.f);
    float s0[3], c0[3], s1[3], c1[3], s2[3], c2[3];
#pragma unroll
    for (int c = 0; c < 3; ++c) {
        __sincosf(sc * L[c], &s0[c], &c0[c]);
        s1[c] = 2.f * s0[c] * c0[c];
        c1[c] = fmaf(c0[c], c0[c], -s0[c] * s0[c]);
        s2[c] = 2.f * s1[c] * c1[c];
        c2[c] = fmaf(c1[c], c1[c], -s1[c] * s1[c]);
    }
    if (qt == 0) {
        v[0]=L[0]; v[1]=L[1]; v[2]=L[2];
        v[3]=s0[0]; v[4]=s0[1]; v[5]=s0[2];
        v[6]=c0[0]; v[7]=c0[1]; v[8]=c0[2];
        v[9]=s1[0]; v[10]=s1[1]; v[11]=s1[2];
        v[12]=c1[0]; v[13]=c1[1]; v[14]=c1[2];
        v[15]=s2[0];
    } else if (qt == 1) {
        v[0]=s0[1]; v[1]=s0[2];
        v[2]=c0[0]; v[3]=c0[1]; v[4]=c0[2];
        v[5]=s1[0]; v[6]=s1[1]; v[7]=s1[2];
        v[8]=c1[0]; v[9]=c1[1]; v[10]=c1[2];
        v[11]=s2[0]; v[12]=s2[1]; v[13]=s2[2];
        v[14]=c2[0]; v[15]=c2[1];
    } else if (qt == 2) {
        v[0]=c0[2];
        v[1]=s1[0]; v[2]=s1[1]; v[3]=s1[2];
        v[4]=c1[0]; v[5]=c1[1]; v[6]=c1[2];
        v[7]=r0.x; v[8]=r1.x; v[9]=r2.x;
        v[10]=1.0f;   // bias feature 42
        v[11]=0.f; v[12]=0.f; v[13]=0.f; v[14]=0.f; v[15]=0.f;
    } else {
#pragma unroll
        for (int t = 0; t < 16; ++t) v[t] = 0.f;
    }
}

// pack v[16] -> X hi/lo planes (hi @0, lo @+2048), R6-proven
__device__ __forceinline__ void writeA16(char* X, int l15, int swz, int qt, const float* v) {
    unsigned h[8], l[8];
#pragma unroll
    for (int p = 0; p < 8; ++p) {
        float a = v[2 * p], b = v[2 * p + 1];
        unsigned ua = __float_as_uint(a), ub = __float_as_uint(b);
        h[p] = (ub & 0xffff0000u) | (ua >> 16);
        float ra = a - __uint_as_float(ua & 0xffff0000u);
        float rb = b - __uint_as_float(ub & 0xffff0000u);
        l[p] = (__float_as_uint(rb) & 0xffff0000u) | (__float_as_uint(ra) >> 16);
    }
    const int cb = qt * 32;
    const int a1 = l15 * 128 + (cb ^ swz);
    const int a2 = l15 * 128 + ((cb + 16) ^ swz);
    *(uint4*)(X + a1) = make_uint4(h[0], h[1], h[2], h[3]);
    *(uint4*)(X + a2) = make_uint4(h[4], h[5], h[6], h[7]);
    *(uint4*)(X + 2048 + a1) = make_uint4(l[0], l[1], l[2], l[3]);
    *(uint4*)(X + 2048 + a2) = make_uint4(l[4], l[5], l[6], l[7]);
}

// A-frags (both ks) from interleaved H plane: 4 b128 reads + 16 v_perm
#define READ_A(H, Ah0, Al0, Ah1, Al1) do {                              \
    uint4 _a = *(const uint4*)((H) + hb00);                             \
    uint4 _b = *(const uint4*)((H) + hb01);                             \
    uint4 _c = *(const uint4*)((H) + hb10);                             \
    uint4 _d = *(const uint4*)((H) + hb11);                             \
    U4S8 _t;                                                            \
    _t.u[0] = __builtin_amdgcn_perm(_a.y, _a.x, 0x05040100u);           \
    _t.u[1] = __builtin_amdgcn_perm(_a.w, _a.z, 0x05040100u);           \
    _t.u[2] = __builtin_amdgcn_perm(_b.y, _b.x, 0x05040100u);           \
    _t.u[3] = __builtin_amdgcn_perm(_b.w, _b.z, 0x05040100u);           \
    Ah0 = _t.s;                                                         \
    _t.u[0] = __builtin_amdgcn_perm(_a.y, _a.x, 0x07060302u);           \
    _t.u[1] = __builtin_amdgcn_perm(_a.w, _a.z, 0x07060302u);           \
    _t.u[2] = __builtin_amdgcn_perm(_b.y, _b.x, 0x07060302u);           \
    _t.u[3] = __builtin_amdgcn_perm(_b.w, _b.z, 0x07060302u);           \
    Al0 = _t.s;                                                         \
    _t.u[0] = __builtin_amdgcn_perm(_c.y, _c.x, 0x05040100u);           \
    _t.u[1] = __builtin_amdgcn_perm(_c.w, _c.z, 0x05040100u);           \
    _t.u[2] = __builtin_amdgcn_perm(_d.y, _d.x, 0x05040100u);           \
    _t.u[3] = __builtin_amdgcn_perm(_d.w, _d.z, 0x05040100u);           \
    Ah1 = _t.s;                                                         \
    _t.u[0] = __builtin_amdgcn_perm(_c.y, _c.x, 0x07060302u);           \
    _t.u[1] = __builtin_amdgcn_perm(_c.w, _c.z, 0x07060302u);           \
    _t.u[2] = __builtin_amdgcn_perm(_d.y, _d.x, 0x07060302u);           \
    _t.u[3] = __builtin_amdgcn_perm(_d.w, _d.z, 0x07060302u);           \
    Al1 = _t.s;                                                         \
} while (0)

// hi/lo 3-term gemm, B fragments in registers
#define GEMM6(ACC, Ah0, Al0, Ah1, Al1, Bh, Bl) do {                     \
    _Pragma("unroll")                                                   \
    for (int _nt = 0; _nt < 4; ++_nt) {                                 \
        f32x4 _x = (ACC)[_nt];                                          \
        _x = __builtin_amdgcn_mfma_f32_16x16x32_bf16(Ah0, (Bh)[0][_nt], _x, 0, 0, 0); \
        _x = __builtin_amdgcn_mfma_f32_16x16x32_bf16(Ah0, (Bl)[0][_nt], _x, 0, 0, 0); \
        _x = __builtin_amdgcn_mfma_f32_16x16x32_bf16(Al0, (Bh)[0][_nt], _x, 0, 0, 0); \
        _x = __builtin_amdgcn_mfma_f32_16x16x32_bf16(Ah1, (Bh)[1][_nt], _x, 0, 0, 0); \
        _x = __builtin_amdgcn_mfma_f32_16x16x32_bf16(Ah1, (Bl)[1][_nt], _x, 0, 0, 0); \
        _x = __builtin_amdgcn_mfma_f32_16x16x32_bf16(Al1, (Bh)[1][_nt], _x, 0, 0, 0); \
        (ACC)[_nt] = _x;                                                \
    }                                                                   \
} while (0)

// C-tile -> interleaved H plane (16 b32 writes), swizzled
#define STORE_H(H, ACC) do {                                            \
    _Pragma("unroll")                                                   \
    for (int _nt = 0; _nt < 4; ++_nt) {                                 \
        _Pragma("unroll")                                               \
        for (int _r = 0; _r < 4; ++_r) {                                \
            int _row = q4 + _r;                                         \
            int _byte = _row * 256 + ((((l15 + 16 * _nt) << 2)) ^ ((_row & 7) << 4)); \
            *(unsigned*)((H) + _byte) = packHL((ACC)[_nt][_r]);         \
        }                                                               \
    }                                                                   \
} while (0)

// ---------------- kernel 1: pre-split W1T(+bias col), W2T, G (hi/lo), g ----------------
__global__ __launch_bounds__(256) void precompute_kernel(
    const float* __restrict__ W1, const float* __restrict__ b1,
    const float* __restrict__ W2,
    const float* __restrict__ W3, const float* __restrict__ b3,
    char* __restrict__ ws)
{
    __shared__ float W3t[128][64];
    const int tid = threadIdx.x;
    for (int e = tid; e < 8192; e += 256) W3t[e & 127][e >> 7] = W3[e];
    __syncthreads();

    unsigned short* w1h = (unsigned short*)(ws + WS_W1H);
    unsigned short* w1l = (unsigned short*)(ws + WS_W1L);
    unsigned short* w2h = (unsigned short*)(ws + WS_W2H);
    unsigned short* w2l = (unsigned short*)(ws + WS_W2L);
    unsigned short* gh  = (unsigned short*)(ws + WS_GH);
    unsigned short* gl  = (unsigned short*)(ws + WS_GL);

    for (int e = tid; e < 4096; e += 256) {       // coalesced reads, scattered writes
        int j = e >> 6, i = e & 63;
        float v1 = (j < 42) ? W1[e] : ((j == 42) ? b1[i] : 0.f);
        unsigned u = __float_as_uint(v1);
        w1h[i * 64 + j] = (unsigned short)(u >> 16);
        float r1 = v1 - __uint_as_float(u & 0xffff0000u);
        w1l[i * 64 + j] = (unsigned short)(__float_as_uint(r1) >> 16);
        float v2 = W2[e];
        u = __float_as_uint(v2);
        w2h[i * 64 + j] = (unsigned short)(u >> 16);
        float r2 = v2 - __uint_as_float(u & 0xffff0000u);
        w2l[i * 64 + j] = (unsigned short)(__float_as_uint(r2) >> 16);
    }
    for (int idx = tid; idx < 4096; idx += 256) {
        int r = idx >> 6, k = idx & 63;
        float a = 0.f;
        for (int d = 0; d < 128; ++d) a = fmaf(W3t[d][r], W3t[d][k], a);
        unsigned h = f2bf(a);
        gh[idx] = (unsigned short)h;
        gl[idx] = (unsigned short)f2bf(a - bfhi(h));
    }
    if (tid < 64) {
        float a = 0.f;
        for (int d = 0; d < 128; ++d) a = fmaf(W3t[d][tid], b3[d], a);
        ((float*)(ws + WS_g))[tid] = a;
    }
}

// ---------------- kernel 2: fused MFMA, 1 scene/block, 1 barrier ----------------
__global__ __launch_bounds__(256, 2) void cam_mfma_kernel(
    const float* __restrict__ input_poses, const float* __restrict__ target_poses,
    const float* __restrict__ b2, const char* __restrict__ ws, float* __restrict__ out)
{
    __shared__ __align__(16) char smem[LDS_BYTES];
    const int tid = threadIdx.x, lane = tid & 63, w = tid >> 6, s = blockIdx.x;
    const int l15 = lane & 15, g = lane >> 4, q4 = g << 2;
    const int swz = (l15 & 7) << 4;
    const int aoff0 = l15 * 128 + ((g << 4) ^ swz);           // X plane frags
    const int aoff1 = l15 * 128 + ((64 + (g << 4)) ^ swz);
    const int hb00 = l15 * 256 + ((32 * g) ^ swz);            // H plane frag chunks
    const int hb01 = l15 * 256 + ((32 * g + 16) ^ swz);
    const int hb10 = l15 * 256 + ((32 * g + 128) ^ swz);
    const int hb11 = l15 * 256 + ((32 * g + 128 + 16) ^ swz);

    char* ZK = smem + L_ZK;
    char* XH = smem + L_XH + (w << 12);
    float* ckF = (float*)(smem + L_CK);

    // resident B fragments (global, L2-hot)
    short8 w1h[2][4], w1l[2][4], w2h[2][4], w2l[2][4];
#pragma unroll
    for (int ks = 0; ks < 2; ++ks)
#pragma unroll
        for (int nt = 0; nt < 4; ++nt) {
            const int off = (l15 + 16 * nt) * 128 + (g << 4) + 64 * ks;
            w1h[ks][nt] = *(const short8*)(ws + WS_W1H + off);
            w1l[ks][nt] = *(const short8*)(ws + WS_W1L + off);
            w2h[ks][nt] = *(const short8*)(ws + WS_W2H + off);
            w2l[ks][nt] = *(const short8*)(ws + WS_W2L + off);
        }
    float b2v[4], gw[4];
#pragma unroll
    for (int nt = 0; nt < 4; ++nt) {
        b2v[nt] = b2[l15 + 16 * nt];
        gw[nt]  = ((const float*)(ws + WS_g))[l15 + 16 * nt];
    }

    short8 Ah0, Al0, Ah1, Al1;
    float v[16];

    // ================= key tile (wave w -> keys 16w..16w+15) =================
    {
        pe_values(v, input_poses + ((size_t)(s * 64 + 16 * w + l15)) * 16, g);
        writeA16(XH, l15, swz, g, v);
        Ah0 = *(const short8*)(XH + aoff0);
        Al0 = *(const short8*)(XH + 2048 + aoff0);
        Ah1 = *(const short8*)(XH + aoff1);
        Al1 = *(const short8*)(XH + 2048 + aoff1);
        f32x4 acc[4];
#pragma unroll
        for (int nt = 0; nt < 4; ++nt) acc[nt] = mk4(0.f);
        GEMM6(acc, Ah0, Al0, Ah1, Al1, w1h, w1l);     // L1 (bias via K-col)
        RELU4(acc);
        STORE_H(XH, acc);                              // H1 over X

        READ_A(XH, Ah0, Al0, Ah1, Al1);
        f32x4 acc2[4];
#pragma unroll
        for (int nt = 0; nt < 4; ++nt) acc2[nt] = mk4(b2v[nt]);
        GEMM6(acc2, Ah0, Al0, Ah1, Al1, w2h, w2l);    // L2
        RELU4(acc2);

        // ck[key] = g . h2k  (reduce own 4 cols, then across l15)
#pragma unroll
        for (int r = 0; r < 4; ++r) {
            float t = acc2[0][r] * gw[0];
            t = fmaf(acc2[1][r], gw[1], t);
            t = fmaf(acc2[2][r], gw[2], t);
            t = fmaf(acc2[3][r], gw[3], t);
            t += __shfl_xor(t, 1);
            t += __shfl_xor(t, 2);
            t += __shfl_xor(t, 4);
            t += __shfl_xor(t, 8);
            if (l15 == 0) ckF[16 * w + q4 + r] = t;
        }
        STORE_H(XH, acc2);                             // H2 over H1

        // Zk = H2k @ G   (G frags streamed from global, transient)
        short8 ggh[2][4], ggl[2][4];
#pragma unroll
        for (int ks = 0; ks < 2; ++ks)
#pragma unroll
            for (int nt = 0; nt < 4; ++nt) {
                const int off = (l15 + 16 * nt) * 128 + (g << 4) + 64 * ks;
                ggh[ks][nt] = *(const short8*)(ws + WS_GH + off);
                ggl[ks][nt] = *(const short8*)(ws + WS_GL + off);
            }
        READ_A(XH, Ah0, Al0, Ah1, Al1);
        f32x4 zacc[4];
#pragma unroll
        for (int nt = 0; nt < 4; ++nt) zacc[nt] = mk4(0.f);
        GEMM6(zacc, Ah0, Al0, Ah1, Al1, ggh, ggl);

        // scatter Zk tile (trunc hi/lo), once per block
#pragma unroll
        for (int nt = 0; nt < 4; ++nt) {
#pragma unroll
            for (int r = 0; r < 4; ++r) {
                int row = 16 * w + q4 + r;
                int byte = row * 128 + (((l15 + 16 * nt) * 2) ^ ((row & 7) << 4));
                float zv = zacc[nt][r];
                unsigned u = __float_as_uint(zv);
                *(unsigned short*)(ZK + byte) = (unsigned short)(u >> 16);
                float res = zv - __uint_as_float(u & 0xffff0000u);
                *(unsigned short*)(ZK + 8192 + byte) =
                    (unsigned short)(__float_as_uint(res) >> 16);
            }
        }
    }
    __syncthreads();   // the ONLY barrier: Zk + ck visible

    // Zk B-frags -> registers (reused by all 4 query tiles)
    short8 zkh[2][4], zkl[2][4];
#pragma unroll
    for (int ks = 0; ks < 2; ++ks)
#pragma unroll
        for (int nt = 0; nt < 4; ++nt) {
            const int zb = (l15 + 16 * nt) * 128 + (((g << 4) + 64 * ks) ^ swz);
            zkh[ks][nt] = *(const short8*)(ZK + zb);
            zkl[ks][nt] = *(const short8*)(ZK + 8192 + zb);
        }
    float ckreg[4];
#pragma unroll
    for (int nt = 0; nt < 4; ++nt) ckreg[nt] = ckF[l15 + 16 * nt];

    // ================= query tiles (4 per wave, barrier-free) =================
    float* outS = out + (size_t)s * 16384;
#pragma unroll 1
    for (int it = 0; it < 4; ++it) {
        const int qbase = (it * 4 + w) * 16;
        pe_values(v, target_poses + ((size_t)(s * 256 + qbase + l15)) * 16, g);
        writeA16(XH, l15, swz, g, v);
        Ah0 = *(const short8*)(XH + aoff0);
        Al0 = *(const short8*)(XH + 2048 + aoff0);
        Ah1 = *(const short8*)(XH + aoff1);
        Al1 = *(const short8*)(XH + 2048 + aoff1);
        f32x4 acc[4];
#pragma unroll
        for (int nt = 0; nt < 4; ++nt) acc[nt] = mk4(0.f);
        GEMM6(acc, Ah0, Al0, Ah1, Al1, w1h, w1l);     // L1
        RELU4(acc);
        STORE_H(XH, acc);

        READ_A(XH, Ah0, Al0, Ah1, Al1);
#pragma unroll
        for (int nt = 0; nt < 4; ++nt) acc[nt] = mk4(b2v[nt]);
        GEMM6(acc, Ah0, Al0, Ah1, Al1, w2h, w2l);     // L2
        RELU4(acc);
        STORE_H(XH, acc);

        READ_A(XH, Ah0, Al0, Ah1, Al1);
#pragma unroll
        for (int nt = 0; nt < 4; ++nt) acc[nt] = mk4(ckreg[nt]);
        GEMM6(acc, Ah0, Al0, Ah1, Al1, zkh, zkl);     // scores (+ck init)

        // softmax over 64 k (R6-proven)
#pragma unroll
        for (int r = 0; r < 4; ++r) {
            float m = fmaxf(fmaxf(acc[0][r], acc[1][r]), fmaxf(acc[2][r], acc[3][r]));
            m = fmaxf(m, __shfl_xor(m, 1));
            m = fmaxf(m, __shfl_xor(m, 2));
            m = fmaxf(m, __shfl_xor(m, 4));
            m = fmaxf(m, __shfl_xor(m, 8));
            float e0 = __expf((acc[0][r] - m) * SCALE);
            float e1 = __expf((acc[1][r] - m) * SCALE);
            float e2 = __expf((acc[2][r] - m) * SCALE);
            float e3 = __expf((acc[3][r] - m) * SCALE);
            float ssum = e0 + e1 + e2 + e3;
            ssum += __shfl_xor(ssum, 1);
            ssum += __shfl_xor(ssum, 2);
            ssum += __shfl_xor(ssum, 4);
            ssum += __shfl_xor(ssum, 8);
            float iv = 1.f / ssum;
            acc[0][r] = e0 * iv; acc[1][r] = e1 * iv;
            acc[2][r] = e2 * iv; acc[3][r] = e3 * iv;
        }
        const int qoff = qbase + q4;
#pragma unroll
        for (int nt = 0; nt < 4; ++nt) {
            int k = l15 + 16 * nt;
            *(float4*)(outS + (size_t)k * 256 + qoff) =
                make_float4(acc[nt][0], acc[nt][1], acc[nt][2], acc[nt][3]);
        }
    }
}

extern "C" void kernel_launch(void* const* d_in, const int* in_sizes, int n_in,
                              void* d_out, int out_size, void* d_ws, size_t ws_size,
                              hipStream_t stream) {
    const float* input_poses  = (const float*)d_in[0];
    const float* target_poses = (const float*)d_in[1];
    const float* W1 = (const float*)d_in[2];
    const float* b1 = (const float*)d_in[3];
    const float* W2 = (const float*)d_in[4];
    const float* b2 = (const float*)d_in[5];
    const float* W3 = (const float*)d_in[6];
    const float* b3 = (const float*)d_in[7];
    float* out = (float*)d_out;
    char* ws = (char*)d_ws;   // uses 49408 bytes

    precompute_kernel<<<dim3(1), dim3(256), 0, stream>>>(W1, b1, W2, W3, b3, ws);
    cam_mfma_kernel<<<dim3(1024), dim3(256), 0, stream>>>(
        input_poses, target_poses, b2, ws, out);
}

// Round 8
// 81.230 us; speedup vs baseline: 1.4120x; 1.4120x over previous
//
#include <hip/hip_runtime.h>
#include <math.h>

typedef __attribute__((ext_vector_type(8))) short short8;
typedef __attribute__((ext_vector_type(4))) float f32x4;

#define SCALE 0.08838834764831845f   // 1/sqrt(128)

// ws byte offsets (total 49408)
#define WS_W1H 0
#define WS_W1L 8192
#define WS_W2H 16384
#define WS_W2L 24576
#define WS_GH  32768
#define WS_GL  40960
#define WS_g   49152

// LDS: W1T hi/lo 16K | G->Zk hi/lo 16K | 4 x 4K per-wave XH | ck 256B = 49408
#define L_W1T 0
#define L_G   16384
#define L_XH  32768
#define L_CK  49152
#define LDS_BYTES 49408

__device__ __forceinline__ unsigned f2bf(float f) {   // RNE
    unsigned u = __float_as_uint(f);
    return (u + 0x7fffu + ((u >> 16) & 1u)) >> 16;
}
__device__ __forceinline__ float bfhi(unsigned h) { return __uint_as_float(h << 16); }
__device__ __forceinline__ f32x4 mk4(float v) { f32x4 r = {v, v, v, v}; return r; }
// interleaved word: (lo16 << 16) | hi16, trunc split
__device__ __forceinline__ unsigned packHL(float v) {
    unsigned u = __float_as_uint(v);
    float res = v - __uint_as_float(u & 0xffff0000u);
    return (__float_as_uint(res) & 0xffff0000u) | (u >> 16);
}
union U4S8 { uint4 u4; unsigned u[4]; short8 s; };

#define RELU4(ACC) do {                                                  \
    _Pragma("unroll")                                                    \
    for (int _n = 0; _n < 4; ++_n) {                                     \
        _Pragma("unroll")                                                \
        for (int _r = 0; _r < 4; ++_r)                                   \
            (ACC)[_n][_r] = fmaxf((ACC)[_n][_r], 0.f);                   \
    }                                                                    \
} while (0)

// ---- per-quarter PE + bias feature 42 = 1.0 (R6/R7-proven) ----
__device__ __forceinline__ void pe_values(float* v, const float* __restrict__ pose, int qt) {
    float2 r0 = *(const float2*)(pose + 2);
    float2 r1 = *(const float2*)(pose + 6);
    float2 r2 = *(const float2*)(pose + 10);
    const float L[3] = {r0.y, r1.y, r2.y};
    const float sc = (qt == 0) ? 1.5f : ((qt == 1) ? 6.f : 24.f);
    float s0[3], c0[3], s1[3], c1[3], s2[3], c2[3];
#pragma unroll
    for (int c = 0; c < 3; ++c) {
        __sincosf(sc * L[c], &s0[c], &c0[c]);
        s1[c] = 2.f * s0[c] * c0[c];
        c1[c] = fmaf(c0[c], c0[c], -s0[c] * s0[c]);
        s2[c] = 2.f * s1[c] * c1[c];
        c2[c] = fmaf(c1[c], c1[c], -s1[c] * s1[c]);
    }
    if (qt == 0) {
        v[0]=L[0]; v[1]=L[1]; v[2]=L[2];
        v[3]=s0[0]; v[4]=s0[1]; v[5]=s0[2];
        v[6]=c0[0]; v[7]=c0[1]; v[8]=c0[2];
        v[9]=s1[0]; v[10]=s1[1]; v[11]=s1[2];
        v[12]=c1[0]; v[13]=c1[1]; v[14]=c1[2];
        v[15]=s2[0];
    } else if (qt == 1) {
        v[0]=s0[1]; v[1]=s0[2];
        v[2]=c0[0]; v[3]=c0[1]; v[4]=c0[2];
        v[5]=s1[0]; v[6]=s1[1]; v[7]=s1[2];
        v[8]=c1[0]; v[9]=c1[1]; v[10]=c1[2];
        v[11]=s2[0]; v[12]=s2[1]; v[13]=s2[2];
        v[14]=c2[0]; v[15]=c2[1];
    } else if (qt == 2) {
        v[0]=c0[2];
        v[1]=s1[0]; v[2]=s1[1]; v[3]=s1[2];
        v[4]=c1[0]; v[5]=c1[1]; v[6]=c1[2];
        v[7]=r0.x; v[8]=r1.x; v[9]=r2.x;
        v[10]=1.0f;   // bias feature 42
        v[11]=0.f; v[12]=0.f; v[13]=0.f; v[14]=0.f; v[15]=0.f;
    } else {
#pragma unroll
        for (int t = 0; t < 16; ++t) v[t] = 0.f;
    }
}

// pack v[16] -> X hi/lo halves of the 4K XH plane
__device__ __forceinline__ void writeA16(char* X, int l15, int swz, int qt, const float* v) {
    unsigned h[8], l[8];
#pragma unroll
    for (int p = 0; p < 8; ++p) {
        float a = v[2 * p], b = v[2 * p + 1];
        unsigned ua = __float_as_uint(a), ub = __float_as_uint(b);
        h[p] = (ub & 0xffff0000u) | (ua >> 16);
        float ra = a - __uint_as_float(ua & 0xffff0000u);
        float rb = b - __uint_as_float(ub & 0xffff0000u);
        l[p] = (__float_as_uint(rb) & 0xffff0000u) | (__float_as_uint(ra) >> 16);
    }
    const int cb = qt * 32;
    const int a1 = l15 * 128 + (cb ^ swz);
    const int a2 = l15 * 128 + ((cb + 16) ^ swz);
    *(uint4*)(X + a1) = make_uint4(h[0], h[1], h[2], h[3]);
    *(uint4*)(X + a2) = make_uint4(h[4], h[5], h[6], h[7]);
    *(uint4*)(X + 2048 + a1) = make_uint4(l[0], l[1], l[2], l[3]);
    *(uint4*)(X + 2048 + a2) = make_uint4(l[4], l[5], l[6], l[7]);
}

// A-frags (both ks) from interleaved H plane: 4 b128 reads + 16 v_perm (R7-proven)
#define READ_A(H, Ah0, Al0, Ah1, Al1) do {                              \
    uint4 _a = *(const uint4*)((H) + hb00);                             \
    uint4 _b = *(const uint4*)((H) + hb01);                             \
    uint4 _c = *(const uint4*)((H) + hb10);                             \
    uint4 _d = *(const uint4*)((H) + hb11);                             \
    U4S8 _t;                                                            \
    _t.u[0] = __builtin_amdgcn_perm(_a.y, _a.x, 0x05040100u);           \
    _t.u[1] = __builtin_amdgcn_perm(_a.w, _a.z, 0x05040100u);           \
    _t.u[2] = __builtin_amdgcn_perm(_b.y, _b.x, 0x05040100u);           \
    _t.u[3] = __builtin_amdgcn_perm(_b.w, _b.z, 0x05040100u);           \
    Ah0 = _t.s;                                                         \
    _t.u[0] = __builtin_amdgcn_perm(_a.y, _a.x, 0x07060302u);           \
    _t.u[1] = __builtin_amdgcn_perm(_a.w, _a.z, 0x07060302u);           \
    _t.u[2] = __builtin_amdgcn_perm(_b.y, _b.x, 0x07060302u);           \
    _t.u[3] = __builtin_amdgcn_perm(_b.w, _b.z, 0x07060302u);           \
    Al0 = _t.s;                                                         \
    _t.u[0] = __builtin_amdgcn_perm(_c.y, _c.x, 0x05040100u);           \
    _t.u[1] = __builtin_amdgcn_perm(_c.w, _c.z, 0x05040100u);           \
    _t.u[2] = __builtin_amdgcn_perm(_d.y, _d.x, 0x05040100u);           \
    _t.u[3] = __builtin_amdgcn_perm(_d.w, _d.z, 0x05040100u);           \
    Ah1 = _t.s;                                                         \
    _t.u[0] = __builtin_amdgcn_perm(_c.y, _c.x, 0x07060302u);           \
    _t.u[1] = __builtin_amdgcn_perm(_c.w, _c.z, 0x07060302u);           \
    _t.u[2] = __builtin_amdgcn_perm(_d.y, _d.x, 0x07060302u);           \
    _t.u[3] = __builtin_amdgcn_perm(_d.w, _d.z, 0x07060302u);           \
    Al1 = _t.s;                                                         \
} while (0)

// hi/lo 3-term gemm, B planes in LDS (hi @BP, lo @BP+8192)
#define GEMM6_LDS(ACC, Ah0, Al0, Ah1, Al1, BP) do {                     \
    _Pragma("unroll")                                                   \
    for (int _nt = 0; _nt < 4; ++_nt) {                                 \
        const char* _b = (BP) + _nt * 2048;                             \
        short8 _bh0 = *(const short8*)(_b + aoff0);                     \
        short8 _bl0 = *(const short8*)(_b + 8192 + aoff0);              \
        short8 _bh1 = *(const short8*)(_b + aoff1);                     \
        short8 _bl1 = *(const short8*)(_b + 8192 + aoff1);              \
        f32x4 _x = (ACC)[_nt];                                          \
        _x = __builtin_amdgcn_mfma_f32_16x16x32_bf16(Ah0, _bh0, _x, 0, 0, 0); \
        _x = __builtin_amdgcn_mfma_f32_16x16x32_bf16(Ah0, _bl0, _x, 0, 0, 0); \
        _x = __builtin_amdgcn_mfma_f32_16x16x32_bf16(Al0, _bh0, _x, 0, 0, 0); \
        _x = __builtin_amdgcn_mfma_f32_16x16x32_bf16(Ah1, _bh1, _x, 0, 0, 0); \
        _x = __builtin_amdgcn_mfma_f32_16x16x32_bf16(Ah1, _bl1, _x, 0, 0, 0); \
        _x = __builtin_amdgcn_mfma_f32_16x16x32_bf16(Al1, _bh1, _x, 0, 0, 0); \
        (ACC)[_nt] = _x;                                                \
    }                                                                   \
} while (0)

// hi/lo 3-term gemm, B fragments in registers (W2T)
#define GEMM6_REG(ACC, Ah0, Al0, Ah1, Al1, Bh, Bl) do {                 \
    _Pragma("unroll")                                                   \
    for (int _nt = 0; _nt < 4; ++_nt) {                                 \
        f32x4 _x = (ACC)[_nt];                                          \
        _x = __builtin_amdgcn_mfma_f32_16x16x32_bf16(Ah0, (Bh)[0][_nt], _x, 0, 0, 0); \
        _x = __builtin_amdgcn_mfma_f32_16x16x32_bf16(Ah0, (Bl)[0][_nt], _x, 0, 0, 0); \
        _x = __builtin_amdgcn_mfma_f32_16x16x32_bf16(Al0, (Bh)[0][_nt], _x, 0, 0, 0); \
        _x = __builtin_amdgcn_mfma_f32_16x16x32_bf16(Ah1, (Bh)[1][_nt], _x, 0, 0, 0); \
        _x = __builtin_amdgcn_mfma_f32_16x16x32_bf16(Ah1, (Bl)[1][_nt], _x, 0, 0, 0); \
        _x = __builtin_amdgcn_mfma_f32_16x16x32_bf16(Al1, (Bh)[1][_nt], _x, 0, 0, 0); \
        (ACC)[_nt] = _x;                                                \
    }                                                                   \
} while (0)

// C-tile -> interleaved H plane (16 b32 writes), swizzled
#define STORE_H(H, ACC) do {                                            \
    _Pragma("unroll")                                                   \
    for (int _nt = 0; _nt < 4; ++_nt) {                                 \
        _Pragma("unroll")                                               \
        for (int _r = 0; _r < 4; ++_r) {                                \
            int _row = q4 + _r;                                         \
            int _byte = _row * 256 + ((((l15 + 16 * _nt) << 2)) ^ ((_row & 7) << 4)); \
            *(unsigned*)((H) + _byte) = packHL((ACC)[_nt][_r]);         \
        }                                                               \
    }                                                                   \
} while (0)

// -------- kernel 1 (8 blocks): pre-split W1T(+bias), W2T, G (hi/lo), g --------
__global__ __launch_bounds__(256) void precompute_kernel(
    const float* __restrict__ W1, const float* __restrict__ b1,
    const float* __restrict__ W2,
    const float* __restrict__ W3, const float* __restrict__ b3,
    char* __restrict__ ws)
{
    __shared__ float W3t[128][64];
    const int tid = threadIdx.x, blk = blockIdx.x;
    for (int e = tid; e < 8192; e += 256) W3t[e & 127][e >> 7] = W3[e];
    __syncthreads();

    unsigned short* gh = (unsigned short*)(ws + WS_GH);
    unsigned short* gl = (unsigned short*)(ws + WS_GL);
    for (int idx = blk * 512 + tid; idx < blk * 512 + 512; idx += 256) {
        int r = idx >> 6, k = idx & 63;
        float a = 0.f;
        for (int d = 0; d < 128; ++d) a = fmaf(W3t[d][r], W3t[d][k], a);
        unsigned h = f2bf(a);
        gh[idx] = (unsigned short)h;
        gl[idx] = (unsigned short)f2bf(a - bfhi(h));
    }
    if (blk == 0) {
        unsigned short* w1h = (unsigned short*)(ws + WS_W1H);
        unsigned short* w1l = (unsigned short*)(ws + WS_W1L);
        unsigned short* w2h = (unsigned short*)(ws + WS_W2H);
        unsigned short* w2l = (unsigned short*)(ws + WS_W2L);
        for (int e = tid; e < 4096; e += 256) {
            int j = e >> 6, i = e & 63;
            float v1 = (j < 42) ? W1[e] : ((j == 42) ? b1[i] : 0.f);
            unsigned u = __float_as_uint(v1);
            w1h[i * 64 + j] = (unsigned short)(u >> 16);
            float r1 = v1 - __uint_as_float(u & 0xffff0000u);
            w1l[i * 64 + j] = (unsigned short)(__float_as_uint(r1) >> 16);
            float v2 = W2[e];
            u = __float_as_uint(v2);
            w2h[i * 64 + j] = (unsigned short)(u >> 16);
            float r2 = v2 - __uint_as_float(u & 0xffff0000u);
            w2l[i * 64 + j] = (unsigned short)(__float_as_uint(r2) >> 16);
        }
        if (tid < 64) {
            float a = 0.f;
            for (int d = 0; d < 128; ++d) a = fmaf(W3t[d][tid], b3[d], a);
            ((float*)(ws + WS_g))[tid] = a;
        }
    }
}

// -------- kernel 2: fused MFMA, 1 scene/block, 3 blocks/CU --------
__global__ __launch_bounds__(256, 3) void cam_mfma_kernel(
    const float* __restrict__ input_poses, const float* __restrict__ target_poses,
    const float* __restrict__ b2, const char* __restrict__ ws, float* __restrict__ out)
{
    __shared__ __align__(16) char smem[LDS_BYTES];
    const int tid = threadIdx.x, lane = tid & 63, w = tid >> 6, s = blockIdx.x;
    const int l15 = lane & 15, g = lane >> 4, q4 = g << 2;
    const int swz = (l15 & 7) << 4;
    const int aoff0 = l15 * 128 + ((g << 4) ^ swz);           // frag offsets (X & B planes)
    const int aoff1 = l15 * 128 + ((64 + (g << 4)) ^ swz);
    const int hb00 = l15 * 256 + ((32 * g) ^ swz);            // H plane chunks
    const int hb01 = l15 * 256 + ((32 * g + 16) ^ swz);
    const int hb10 = l15 * 256 + ((32 * g + 128) ^ swz);
    const int hb11 = l15 * 256 + ((32 * g + 128 + 16) ^ swz);

    char* ZK = smem + L_G;
    char* XH = smem + L_XH + (w << 12);
    float* ckF = (float*)(smem + L_CK);

    // ---- stage W1T and G planes from pre-split ws (u32 copies, swizzled) ----
    {
        const unsigned* srcW1 = (const unsigned*)(ws + WS_W1H);   // hi then lo (8K each)
        const unsigned* srcG  = (const unsigned*)(ws + WS_GH);
#pragma unroll
        for (int half = 0; half < 2; ++half) {                    // hi, lo
            for (int e = tid; e < 2048; e += 256) {
                int n = e >> 5, cu = e & 31;
                int byte = n * 128 + ((cu * 4) ^ ((n & 7) << 4));
                *(unsigned*)(smem + L_W1T + half * 8192 + byte) = srcW1[half * 2048 + e];
                *(unsigned*)(smem + L_G   + half * 8192 + byte) = srcG [half * 2048 + e];
            }
        }
    }
    // resident W2T fragments + b2 + g
    short8 w2h[2][4], w2l[2][4];
#pragma unroll
    for (int ks = 0; ks < 2; ++ks)
#pragma unroll
        for (int nt = 0; nt < 4; ++nt) {
            const int off = (l15 + 16 * nt) * 128 + (g << 4) + 64 * ks;
            w2h[ks][nt] = *(const short8*)(ws + WS_W2H + off);
            w2l[ks][nt] = *(const short8*)(ws + WS_W2L + off);
        }
    float b2v[4], gw[4];
#pragma unroll
    for (int nt = 0; nt < 4; ++nt) {
        b2v[nt] = b2[l15 + 16 * nt];
        gw[nt]  = ((const float*)(ws + WS_g))[l15 + 16 * nt];
    }

    short8 Ah0, Al0, Ah1, Al1;
    float v[16];

    // prepare key-tile A while staging writes land
    pe_values(v, input_poses + ((size_t)(s * 64 + 16 * w + l15)) * 16, g);
    __syncthreads();   // barrier 0: W1T/G staged

    // ================= key tile (wave w -> keys 16w..16w+15) =================
    f32x4 zacc[4];
    {
        writeA16(XH, l15, swz, g, v);
        Ah0 = *(const short8*)(XH + aoff0);
        Al0 = *(const short8*)(XH + 2048 + aoff0);
        Ah1 = *(const short8*)(XH + aoff1);
        Al1 = *(const short8*)(XH + 2048 + aoff1);
        f32x4 acc[4];
#pragma unroll
        for (int nt = 0; nt < 4; ++nt) acc[nt] = mk4(0.f);
        GEMM6_LDS(acc, Ah0, Al0, Ah1, Al1, smem + L_W1T);   // L1 (bias via K-col)
        RELU4(acc);
        STORE_H(XH, acc);                                    // H1

        READ_A(XH, Ah0, Al0, Ah1, Al1);
#pragma unroll
        for (int nt = 0; nt < 4; ++nt) acc[nt] = mk4(b2v[nt]);
        GEMM6_REG(acc, Ah0, Al0, Ah1, Al1, w2h, w2l);        // L2
        RELU4(acc);

        // ck[key] = g . h2k
#pragma unroll
        for (int r = 0; r < 4; ++r) {
            float t = acc[0][r] * gw[0];
            t = fmaf(acc[1][r], gw[1], t);
            t = fmaf(acc[2][r], gw[2], t);
            t = fmaf(acc[3][r], gw[3], t);
            t += __shfl_xor(t, 1);
            t += __shfl_xor(t, 2);
            t += __shfl_xor(t, 4);
            t += __shfl_xor(t, 8);
            if (l15 == 0) ckF[16 * w + q4 + r] = t;
        }
        STORE_H(XH, acc);                                    // H2

        READ_A(XH, Ah0, Al0, Ah1, Al1);
#pragma unroll
        for (int nt = 0; nt < 4; ++nt) zacc[nt] = mk4(0.f);
        GEMM6_LDS(zacc, Ah0, Al0, Ah1, Al1, smem + L_G);     // Zk = H2k @ G
    }
    // prefetch query tile 0 PE (fills barrier shadow)
    pe_values(v, target_poses + ((size_t)(s * 256 + w * 16 + l15)) * 16, g);
    __syncthreads();   // barrier 1: all G reads + ck writes done

    // scatter Zk tile over G (trunc hi/lo), swizzled B-plane layout
#pragma unroll
    for (int nt = 0; nt < 4; ++nt) {
#pragma unroll
        for (int r = 0; r < 4; ++r) {
            int row = 16 * w + q4 + r;
            int byte = row * 128 + (((l15 + 16 * nt) * 2) ^ ((row & 7) << 4));
            float zv = zacc[nt][r];
            unsigned u = __float_as_uint(zv);
            *(unsigned short*)(ZK + byte) = (unsigned short)(u >> 16);
            float res = zv - __uint_as_float(u & 0xffff0000u);
            *(unsigned short*)(ZK + 8192 + byte) = (unsigned short)(__float_as_uint(res) >> 16);
        }
    }
    writeA16(XH, l15, swz, g, v);      // tile 0 A (own plane, no cross-wave hazard)
    __syncthreads();   // barrier 2: Zk + ck visible
    float ckreg[4];
#pragma unroll
    for (int nt = 0; nt < 4; ++nt) ckreg[nt] = ckF[l15 + 16 * nt];

    // ================= query tiles (4 per wave, barrier-free) =================
    float* outS = out + (size_t)s * 16384;
#pragma unroll 1
    for (int it = 0; it < 4; ++it) {
        Ah0 = *(const short8*)(XH + aoff0);
        Al0 = *(const short8*)(XH + 2048 + aoff0);
        Ah1 = *(const short8*)(XH + aoff1);
        Al1 = *(const short8*)(XH + 2048 + aoff1);
        f32x4 acc[4];
#pragma unroll
        for (int nt = 0; nt < 4; ++nt) acc[nt] = mk4(0.f);
        GEMM6_LDS(acc, Ah0, Al0, Ah1, Al1, smem + L_W1T);    // L1
        RELU4(acc);
        STORE_H(XH, acc);

        READ_A(XH, Ah0, Al0, Ah1, Al1);
#pragma unroll
        for (int nt = 0; nt < 4; ++nt) acc[nt] = mk4(b2v[nt]);
        GEMM6_REG(acc, Ah0, Al0, Ah1, Al1, w2h, w2l);        // L2
        RELU4(acc);
        STORE_H(XH, acc);

        READ_A(XH, Ah0, Al0, Ah1, Al1);
#pragma unroll
        for (int nt = 0; nt < 4; ++nt) acc[nt] = mk4(ckreg[nt]);
        GEMM6_LDS(acc, Ah0, Al0, Ah1, Al1, smem + L_G);      // scores (B = Zk)

        // prefetch next tile PE + A-write (X free after last READ_A; same-wave DS in order)
        if (it < 3) {
            pe_values(v, target_poses +
                      ((size_t)(s * 256 + ((it + 1) * 4 + w) * 16 + l15)) * 16, g);
            writeA16(XH, l15, swz, g, v);
        }

        // softmax over 64 k
#pragma unroll
        for (int r = 0; r < 4; ++r) {
            float m = fmaxf(fmaxf(acc[0][r], acc[1][r]), fmaxf(acc[2][r], acc[3][r]));
            m = fmaxf(m, __shfl_xor(m, 1));
            m = fmaxf(m, __shfl_xor(m, 2));
            m = fmaxf(m, __shfl_xor(m, 4));
            m = fmaxf(m, __shfl_xor(m, 8));
            float e0 = __expf((acc[0][r] - m) * SCALE);
            float e1 = __expf((acc[1][r] - m) * SCALE);
            float e2 = __expf((acc[2][r] - m) * SCALE);
            float e3 = __expf((acc[3][r] - m) * SCALE);
            float ssum = e0 + e1 + e2 + e3;
            ssum += __shfl_xor(ssum, 1);
            ssum += __shfl_xor(ssum, 2);
            ssum += __shfl_xor(ssum, 4);
            ssum += __shfl_xor(ssum, 8);
            float iv = 1.f / ssum;
            acc[0][r] = e0 * iv; acc[1][r] = e1 * iv;
            acc[2][r] = e2 * iv; acc[3][r] = e3 * iv;
        }
        const int qoff = (it * 4 + w) * 16 + q4;
#pragma unroll
        for (int nt = 0; nt < 4; ++nt) {
            int k = l15 + 16 * nt;
            *(float4*)(outS + (size_t)k * 256 + qoff) =
                make_float4(acc[nt][0], acc[nt][1], acc[nt][2], acc[nt][3]);
        }
    }
}

extern "C" void kernel_launch(void* const* d_in, const int* in_sizes, int n_in,
                              void* d_out, int out_size, void* d_ws, size_t ws_size,
                              hipStream_t stream) {
    const float* input_poses  = (const float*)d_in[0];
    const float* target_poses = (const float*)d_in[1];
    const float* W1 = (const float*)d_in[2];
    const float* b1 = (const float*)d_in[3];
    const float* W2 = (const float*)d_in[4];
    const float* b2 = (const float*)d_in[5];
    const float* W3 = (const float*)d_in[6];
    const float* b3 = (const float*)d_in[7];
    float* out = (float*)d_out;
    char* ws = (char*)d_ws;   // uses 49408 bytes

    precompute_kernel<<<dim3(8), dim3(256), 0, stream>>>(W1, b1, W2, W3, b3, ws);
    cam_mfma_kernel<<<dim3(1024), dim3(256), 0, stream>>>(
        input_poses, target_poses, b2, ws, out);
}

// Round 9
// 74.935 us; speedup vs baseline: 1.5306x; 1.0840x over previous
//
#include <hip/hip_runtime.h>
#include <math.h>

typedef __attribute__((ext_vector_type(8))) short short8;
typedef __attribute__((ext_vector_type(4))) float f32x4;

#define SCALE 0.08838834764831845f   // 1/sqrt(128)

// ws byte offsets (total 49408)
#define WS_W1H 0
#define WS_W1L 8192
#define WS_W2H 16384
#define WS_W2L 24576
#define WS_GH  32768
#define WS_GL  40960
#define WS_g   49152

// LDS: W1T hi/lo 16K | G->Zk hi/lo 16K | 4 waves x 2 planes x 4K | ck 256B
#define L_W1T 0
#define L_G   16384
#define L_XH  32768
#define L_CK  65536
#define LDS_BYTES 65792

__device__ __forceinline__ unsigned f2bf(float f) {   // RNE
    unsigned u = __float_as_uint(f);
    return (u + 0x7fffu + ((u >> 16) & 1u)) >> 16;
}
__device__ __forceinline__ float bfhi(unsigned h) { return __uint_as_float(h << 16); }
__device__ __forceinline__ f32x4 mk4(float v) { f32x4 r = {v, v, v, v}; return r; }
// interleaved word: (lo16 << 16) | hi16, trunc split
__device__ __forceinline__ unsigned packHL(float v) {
    unsigned u = __float_as_uint(v);
    float res = v - __uint_as_float(u & 0xffff0000u);
    return (__float_as_uint(res) & 0xffff0000u) | (u >> 16);
}
union U4S8 { uint4 u4; unsigned u[4]; short8 s; };

#define RELU4(ACC) do {                                                  \
    _Pragma("unroll")                                                    \
    for (int _n = 0; _n < 4; ++_n) {                                     \
        _Pragma("unroll")                                                \
        for (int _r = 0; _r < 4; ++_r)                                   \
            (ACC)[_n][_r] = fmaxf((ACC)[_n][_r], 0.f);                   \
    }                                                                    \
} while (0)

// ---- per-quarter PE + bias feature 42 = 1.0 (R6/R7-proven) ----
__device__ __forceinline__ void pe_values(float* v, const float* __restrict__ pose, int qt) {
    float2 r0 = *(const float2*)(pose + 2);
    float2 r1 = *(const float2*)(pose + 6);
    float2 r2 = *(const float2*)(pose + 10);
    const float L[3] = {r0.y, r1.y, r2.y};
    const float sc = (qt == 0) ? 1.5f : ((qt == 1) ? 6.f : 24.f);
    float s0[3], c0[3], s1[3], c1[3], s2[3], c2[3];
#pragma unroll
    for (int c = 0; c < 3; ++c) {
        __sincosf(sc * L[c], &s0[c], &c0[c]);
        s1[c] = 2.f * s0[c] * c0[c];
        c1[c] = fmaf(c0[c], c0[c], -s0[c] * s0[c]);
        s2[c] = 2.f * s1[c] * c1[c];
        c2[c] = fmaf(c1[c], c1[c], -s1[c] * s1[c]);
    }
    if (qt == 0) {
        v[0]=L[0]; v[1]=L[1]; v[2]=L[2];
        v[3]=s0[0]; v[4]=s0[1]; v[5]=s0[2];
        v[6]=c0[0]; v[7]=c0[1]; v[8]=c0[2];
        v[9]=s1[0]; v[10]=s1[1]; v[11]=s1[2];
        v[12]=c1[0]; v[13]=c1[1]; v[14]=c1[2];
        v[15]=s2[0];
    } else if (qt == 1) {
        v[0]=s0[1]; v[1]=s0[2];
        v[2]=c0[0]; v[3]=c0[1]; v[4]=c0[2];
        v[5]=s1[0]; v[6]=s1[1]; v[7]=s1[2];
        v[8]=c1[0]; v[9]=c1[1]; v[10]=c1[2];
        v[11]=s2[0]; v[12]=s2[1]; v[13]=s2[2];
        v[14]=c2[0]; v[15]=c2[1];
    } else if (qt == 2) {
        v[0]=c0[2];
        v[1]=s1[0]; v[2]=s1[1]; v[3]=s1[2];
        v[4]=c1[0]; v[5]=c1[1]; v[6]=c1[2];
        v[7]=r0.x; v[8]=r1.x; v[9]=r2.x;
        v[10]=1.0f;   // bias feature 42
        v[11]=0.f; v[12]=0.f; v[13]=0.f; v[14]=0.f; v[15]=0.f;
    } else {
#pragma unroll
        for (int t = 0; t < 16; ++t) v[t] = 0.f;
    }
}

// pack v[16] -> X hi/lo halves of a 4K plane
__device__ __forceinline__ void writeA16(char* X, int l15, int swz, int qt, const float* v) {
    unsigned h[8], l[8];
#pragma unroll
    for (int p = 0; p < 8; ++p) {
        float a = v[2 * p], b = v[2 * p + 1];
        unsigned ua = __float_as_uint(a), ub = __float_as_uint(b);
        h[p] = (ub & 0xffff0000u) | (ua >> 16);
        float ra = a - __uint_as_float(ua & 0xffff0000u);
        float rb = b - __uint_as_float(ub & 0xffff0000u);
        l[p] = (__float_as_uint(rb) & 0xffff0000u) | (__float_as_uint(ra) >> 16);
    }
    const int cb = qt * 32;
    const int a1 = l15 * 128 + (cb ^ swz);
    const int a2 = l15 * 128 + ((cb + 16) ^ swz);
    *(uint4*)(X + a1) = make_uint4(h[0], h[1], h[2], h[3]);
    *(uint4*)(X + a2) = make_uint4(h[4], h[5], h[6], h[7]);
    *(uint4*)(X + 2048 + a1) = make_uint4(l[0], l[1], l[2], l[3]);
    *(uint4*)(X + 2048 + a2) = make_uint4(l[4], l[5], l[6], l[7]);
}

// A-frags (both ks) from interleaved H plane: 4 b128 reads + 16 v_perm
#define READ_A(H, Ah0, Al0, Ah1, Al1) do {                              \
    uint4 _a = *(const uint4*)((H) + hb00);                             \
    uint4 _b = *(const uint4*)((H) + hb01);                             \
    uint4 _c = *(const uint4*)((H) + hb10);                             \
    uint4 _d = *(const uint4*)((H) + hb11);                             \
    U4S8 _t;                                                            \
    _t.u[0] = __builtin_amdgcn_perm(_a.y, _a.x, 0x05040100u);           \
    _t.u[1] = __builtin_amdgcn_perm(_a.w, _a.z, 0x05040100u);           \
    _t.u[2] = __builtin_amdgcn_perm(_b.y, _b.x, 0x05040100u);           \
    _t.u[3] = __builtin_amdgcn_perm(_b.w, _b.z, 0x05040100u);           \
    Ah0 = _t.s;                                                         \
    _t.u[0] = __builtin_amdgcn_perm(_a.y, _a.x, 0x07060302u);           \
    _t.u[1] = __builtin_amdgcn_perm(_a.w, _a.z, 0x07060302u);           \
    _t.u[2] = __builtin_amdgcn_perm(_b.y, _b.x, 0x07060302u);           \
    _t.u[3] = __builtin_amdgcn_perm(_b.w, _b.z, 0x07060302u);           \
    Al0 = _t.s;                                                         \
    _t.u[0] = __builtin_amdgcn_perm(_c.y, _c.x, 0x05040100u);           \
    _t.u[1] = __builtin_amdgcn_perm(_c.w, _c.z, 0x05040100u);           \
    _t.u[2] = __builtin_amdgcn_perm(_d.y, _d.x, 0x05040100u);           \
    _t.u[3] = __builtin_amdgcn_perm(_d.w, _d.z, 0x05040100u);           \
    Ah1 = _t.s;                                                         \
    _t.u[0] = __builtin_amdgcn_perm(_c.y, _c.x, 0x07060302u);           \
    _t.u[1] = __builtin_amdgcn_perm(_c.w, _c.z, 0x07060302u);           \
    _t.u[2] = __builtin_amdgcn_perm(_d.y, _d.x, 0x07060302u);           \
    _t.u[3] = __builtin_amdgcn_perm(_d.w, _d.z, 0x07060302u);           \
    Al1 = _t.s;                                                         \
} while (0)

// hi/lo 3-term gemm, B planes in LDS (hi @BP, lo @BP+8192)
#define GEMM6_LDS(ACC, Ah0, Al0, Ah1, Al1, BP) do {                     \
    _Pragma("unroll")                                                   \
    for (int _nt = 0; _nt < 4; ++_nt) {                                 \
        const char* _b = (BP) + _nt * 2048;                             \
        short8 _bh0 = *(const short8*)(_b + aoff0);                     \
        short8 _bl0 = *(const short8*)(_b + 8192 + aoff0);              \
        short8 _bh1 = *(const short8*)(_b + aoff1);                     \
        short8 _bl1 = *(const short8*)(_b + 8192 + aoff1);              \
        f32x4 _x = (ACC)[_nt];                                          \
        _x = __builtin_amdgcn_mfma_f32_16x16x32_bf16(Ah0, _bh0, _x, 0, 0, 0); \
        _x = __builtin_amdgcn_mfma_f32_16x16x32_bf16(Ah0, _bl0, _x, 0, 0, 0); \
        _x = __builtin_amdgcn_mfma_f32_16x16x32_bf16(Al0, _bh0, _x, 0, 0, 0); \
        _x = __builtin_amdgcn_mfma_f32_16x16x32_bf16(Ah1, _bh1, _x, 0, 0, 0); \
        _x = __builtin_amdgcn_mfma_f32_16x16x32_bf16(Ah1, _bl1, _x, 0, 0, 0); \
        _x = __builtin_amdgcn_mfma_f32_16x16x32_bf16(Al1, _bh1, _x, 0, 0, 0); \
        (ACC)[_nt] = _x;                                                \
    }                                                                   \
} while (0)

// hi/lo 3-term gemm, B fragments in registers (W2T)
#define GEMM6_REG(ACC, Ah0, Al0, Ah1, Al1, Bh, Bl) do {                 \
    _Pragma("unroll")                                                   \
    for (int _nt = 0; _nt < 4; ++_nt) {                                 \
        f32x4 _x = (ACC)[_nt];                                          \
        _x = __builtin_amdgcn_mfma_f32_16x16x32_bf16(Ah0, (Bh)[0][_nt], _x, 0, 0, 0); \
        _x = __builtin_amdgcn_mfma_f32_16x16x32_bf16(Ah0, (Bl)[0][_nt], _x, 0, 0, 0); \
        _x = __builtin_amdgcn_mfma_f32_16x16x32_bf16(Al0, (Bh)[0][_nt], _x, 0, 0, 0); \
        _x = __builtin_amdgcn_mfma_f32_16x16x32_bf16(Ah1, (Bh)[1][_nt], _x, 0, 0, 0); \
        _x = __builtin_amdgcn_mfma_f32_16x16x32_bf16(Ah1, (Bl)[1][_nt], _x, 0, 0, 0); \
        _x = __builtin_amdgcn_mfma_f32_16x16x32_bf16(Al1, (Bh)[1][_nt], _x, 0, 0, 0); \
        (ACC)[_nt] = _x;                                                \
    }                                                                   \
} while (0)

// C-tile -> interleaved H plane (16 b32 writes), swizzled
#define STORE_H(H, ACC) do {                                            \
    _Pragma("unroll")                                                   \
    for (int _nt = 0; _nt < 4; ++_nt) {                                 \
        _Pragma("unroll")                                               \
        for (int _r = 0; _r < 4; ++_r) {                                \
            int _row = q4 + _r;                                         \
            int _byte = _row * 256 + ((((l15 + 16 * _nt) << 2)) ^ ((_row & 7) << 4)); \
            *(unsigned*)((H) + _byte) = packHL((ACC)[_nt][_r]);         \
        }                                                               \
    }                                                                   \
} while (0)

#define SOFTMAX_STORE(ACC, QOFF) do {                                   \
    _Pragma("unroll")                                                   \
    for (int _r = 0; _r < 4; ++_r) {                                    \
        float _m = fmaxf(fmaxf((ACC)[0][_r], (ACC)[1][_r]),             \
                         fmaxf((ACC)[2][_r], (ACC)[3][_r]));            \
        _m = fmaxf(_m, __shfl_xor(_m, 1));                              \
        _m = fmaxf(_m, __shfl_xor(_m, 2));                              \
        _m = fmaxf(_m, __shfl_xor(_m, 4));                              \
        _m = fmaxf(_m, __shfl_xor(_m, 8));                              \
        float _e0 = __expf(((ACC)[0][_r] - _m) * SCALE);                \
        float _e1 = __expf(((ACC)[1][_r] - _m) * SCALE);                \
        float _e2 = __expf(((ACC)[2][_r] - _m) * SCALE);                \
        float _e3 = __expf(((ACC)[3][_r] - _m) * SCALE);                \
        float _ss = _e0 + _e1 + _e2 + _e3;                              \
        _ss += __shfl_xor(_ss, 1);                                      \
        _ss += __shfl_xor(_ss, 2);                                      \
        _ss += __shfl_xor(_ss, 4);                                      \
        _ss += __shfl_xor(_ss, 8);                                      \
        float _iv = 1.f / _ss;                                          \
        (ACC)[0][_r] = _e0 * _iv; (ACC)[1][_r] = _e1 * _iv;             \
        (ACC)[2][_r] = _e2 * _iv; (ACC)[3][_r] = _e3 * _iv;             \
    }                                                                   \
    _Pragma("unroll")                                                   \
    for (int _nt = 0; _nt < 4; ++_nt) {                                 \
        int _k = l15 + 16 * _nt;                                        \
        *(float4*)(outS + (size_t)_k * 256 + (QOFF)) =                  \
            make_float4((ACC)[_nt][0], (ACC)[_nt][1],                   \
                        (ACC)[_nt][2], (ACC)[_nt][3]);                  \
    }                                                                   \
} while (0)

// -------- kernel 1 (8 blocks): pre-split W1T(+bias), W2T, G (hi/lo), g --------
__global__ __launch_bounds__(256) void precompute_kernel(
    const float* __restrict__ W1, const float* __restrict__ b1,
    const float* __restrict__ W2,
    const float* __restrict__ W3, const float* __restrict__ b3,
    char* __restrict__ ws)
{
    __shared__ float W3t[128][64];
    const int tid = threadIdx.x, blk = blockIdx.x;
    for (int e = tid; e < 8192; e += 256) W3t[e & 127][e >> 7] = W3[e];
    __syncthreads();

    unsigned short* gh = (unsigned short*)(ws + WS_GH);
    unsigned short* gl = (unsigned short*)(ws + WS_GL);
    for (int idx = blk * 512 + tid; idx < blk * 512 + 512; idx += 256) {
        int r = idx >> 6, k = idx & 63;
        float a = 0.f;
        for (int d = 0; d < 128; ++d) a = fmaf(W3t[d][r], W3t[d][k], a);
        unsigned h = f2bf(a);
        gh[idx] = (unsigned short)h;
        gl[idx] = (unsigned short)f2bf(a - bfhi(h));
    }
    if (blk == 0) {
        unsigned short* w1h = (unsigned short*)(ws + WS_W1H);
        unsigned short* w1l = (unsigned short*)(ws + WS_W1L);
        unsigned short* w2h = (unsigned short*)(ws + WS_W2H);
        unsigned short* w2l = (unsigned short*)(ws + WS_W2L);
        for (int e = tid; e < 4096; e += 256) {
            int j = e >> 6, i = e & 63;
            float v1 = (j < 42) ? W1[e] : ((j == 42) ? b1[i] : 0.f);
            unsigned u = __float_as_uint(v1);
            w1h[i * 64 + j] = (unsigned short)(u >> 16);
            float r1 = v1 - __uint_as_float(u & 0xffff0000u);
            w1l[i * 64 + j] = (unsigned short)(__float_as_uint(r1) >> 16);
            float v2 = W2[e];
            u = __float_as_uint(v2);
            w2h[i * 64 + j] = (unsigned short)(u >> 16);
            float r2 = v2 - __uint_as_float(u & 0xffff0000u);
            w2l[i * 64 + j] = (unsigned short)(__float_as_uint(r2) >> 16);
        }
        if (tid < 64) {
            float a = 0.f;
            for (int d = 0; d < 128; ++d) a = fmaf(W3t[d][tid], b3[d], a);
            ((float*)(ws + WS_g))[tid] = a;
        }
    }
}

// -------- kernel 2: fused MFMA, 1 scene/block, 2-tile ILP query loop --------
__global__ __launch_bounds__(256, 2) void cam_mfma_kernel(
    const float* __restrict__ input_poses, const float* __restrict__ target_poses,
    const float* __restrict__ b2, const char* __restrict__ ws, float* __restrict__ out)
{
    __shared__ __align__(16) char smem[LDS_BYTES];
    const int tid = threadIdx.x, lane = tid & 63, w = tid >> 6, s = blockIdx.x;
    const int l15 = lane & 15, g = lane >> 4, q4 = g << 2;
    const int swz = (l15 & 7) << 4;
    const int aoff0 = l15 * 128 + ((g << 4) ^ swz);           // frag offsets (X & B planes)
    const int aoff1 = l15 * 128 + ((64 + (g << 4)) ^ swz);
    const int hb00 = l15 * 256 + ((32 * g) ^ swz);            // H plane chunks
    const int hb01 = l15 * 256 + ((32 * g + 16) ^ swz);
    const int hb10 = l15 * 256 + ((32 * g + 128) ^ swz);
    const int hb11 = l15 * 256 + ((32 * g + 128 + 16) ^ swz);

    char* ZK = smem + L_G;
    char* XA = smem + L_XH + (w << 13);          // plane A (4K)
    char* XB = XA + 4096;                        // plane B (4K)
    float* ckF = (float*)(smem + L_CK);

    // ---- stage W1T and G planes from pre-split ws (u32 copies, swizzled) ----
    {
        const unsigned* srcW1 = (const unsigned*)(ws + WS_W1H);
        const unsigned* srcG  = (const unsigned*)(ws + WS_GH);
#pragma unroll
        for (int half = 0; half < 2; ++half) {
            for (int e = tid; e < 2048; e += 256) {
                int n = e >> 5, cu = e & 31;
                int byte = n * 128 + ((cu * 4) ^ ((n & 7) << 4));
                *(unsigned*)(smem + L_W1T + half * 8192 + byte) = srcW1[half * 2048 + e];
                *(unsigned*)(smem + L_G   + half * 8192 + byte) = srcG [half * 2048 + e];
            }
        }
    }
    // resident W2T fragments + b2 + g
    short8 w2h[2][4], w2l[2][4];
#pragma unroll
    for (int ks = 0; ks < 2; ++ks)
#pragma unroll
        for (int nt = 0; nt < 4; ++nt) {
            const int off = (l15 + 16 * nt) * 128 + (g << 4) + 64 * ks;
            w2h[ks][nt] = *(const short8*)(ws + WS_W2H + off);
            w2l[ks][nt] = *(const short8*)(ws + WS_W2L + off);
        }
    float b2v[4], gw[4];
#pragma unroll
    for (int nt = 0; nt < 4; ++nt) {
        b2v[nt] = b2[l15 + 16 * nt];
        gw[nt]  = ((const float*)(ws + WS_g))[l15 + 16 * nt];
    }

    short8 Ah0, Al0, Ah1, Al1;
    float vA[16], vB[16];

    pe_values(vA, input_poses + ((size_t)(s * 64 + 16 * w + l15)) * 16, g);
    __syncthreads();   // barrier 0: W1T/G staged

    // ================= key tile (wave w -> keys 16w..16w+15) =================
    f32x4 zacc[4];
    {
        writeA16(XA, l15, swz, g, vA);
        Ah0 = *(const short8*)(XA + aoff0);
        Al0 = *(const short8*)(XA + 2048 + aoff0);
        Ah1 = *(const short8*)(XA + aoff1);
        Al1 = *(const short8*)(XA + 2048 + aoff1);
        f32x4 acc[4];
#pragma unroll
        for (int nt = 0; nt < 4; ++nt) acc[nt] = mk4(0.f);
        GEMM6_LDS(acc, Ah0, Al0, Ah1, Al1, smem + L_W1T);   // L1 (bias via K-col)
        RELU4(acc);
        STORE_H(XA, acc);                                    // H1

        READ_A(XA, Ah0, Al0, Ah1, Al1);
#pragma unroll
        for (int nt = 0; nt < 4; ++nt) acc[nt] = mk4(b2v[nt]);
        GEMM6_REG(acc, Ah0, Al0, Ah1, Al1, w2h, w2l);        // L2
        RELU4(acc);

        // ck[key] = g . h2k
#pragma unroll
        for (int r = 0; r < 4; ++r) {
            float t = acc[0][r] * gw[0];
            t = fmaf(acc[1][r], gw[1], t);
            t = fmaf(acc[2][r], gw[2], t);
            t = fmaf(acc[3][r], gw[3], t);
            t += __shfl_xor(t, 1);
            t += __shfl_xor(t, 2);
            t += __shfl_xor(t, 4);
            t += __shfl_xor(t, 8);
            if (l15 == 0) ckF[16 * w + q4 + r] = t;
        }
        STORE_H(XA, acc);                                    // H2

        READ_A(XA, Ah0, Al0, Ah1, Al1);
#pragma unroll
        for (int nt = 0; nt < 4; ++nt) zacc[nt] = mk4(0.f);
        GEMM6_LDS(zacc, Ah0, Al0, Ah1, Al1, smem + L_G);     // Zk = H2k @ G
    }
    // prefetch query tile pair 0 PE (fills barrier shadow)
    pe_values(vA, target_poses + ((size_t)(s * 256 + (w) * 16 + l15)) * 16, g);
    pe_values(vB, target_poses + ((size_t)(s * 256 + (4 + w) * 16 + l15)) * 16, g);
    __syncthreads();   // barrier 1: all G reads + ck writes done

    // scatter Zk tile over G (trunc hi/lo), swizzled B-plane layout
#pragma unroll
    for (int nt = 0; nt < 4; ++nt) {
#pragma unroll
        for (int r = 0; r < 4; ++r) {
            int row = 16 * w + q4 + r;
            int byte = row * 128 + (((l15 + 16 * nt) * 2) ^ ((row & 7) << 4));
            float zv = zacc[nt][r];
            unsigned u = __float_as_uint(zv);
            *(unsigned short*)(ZK + byte) = (unsigned short)(u >> 16);
            float res = zv - __uint_as_float(u & 0xffff0000u);
            *(unsigned short*)(ZK + 8192 + byte) = (unsigned short)(__float_as_uint(res) >> 16);
        }
    }
    writeA16(XA, l15, swz, g, vA);     // pair-0 A tiles (own planes, no cross-wave hazard)
    writeA16(XB, l15, swz, g, vB);
    __syncthreads();   // barrier 2: Zk + ck visible
    float ckreg[4];
#pragma unroll
    for (int nt = 0; nt < 4; ++nt) ckreg[nt] = ckF[l15 + 16 * nt];

    // ========= query tile pairs: wave w does tiles (8p+w, 8p+4+w), p=0,1 =========
    float* outS = out + (size_t)s * 16384;
    short8 Bh0, Bl0, Bh1, Bl1;
#pragma unroll 1
    for (int p = 0; p < 2; ++p) {
        f32x4 accA[4], accB[4];
        // ---- phase 1: L1 both tiles ----
        Ah0 = *(const short8*)(XA + aoff0);
        Al0 = *(const short8*)(XA + 2048 + aoff0);
        Ah1 = *(const short8*)(XA + aoff1);
        Al1 = *(const short8*)(XA + 2048 + aoff1);
        Bh0 = *(const short8*)(XB + aoff0);
        Bl0 = *(const short8*)(XB + 2048 + aoff0);
        Bh1 = *(const short8*)(XB + aoff1);
        Bl1 = *(const short8*)(XB + 2048 + aoff1);
#pragma unroll
        for (int nt = 0; nt < 4; ++nt) { accA[nt] = mk4(0.f); accB[nt] = mk4(0.f); }
        GEMM6_LDS(accA, Ah0, Al0, Ah1, Al1, smem + L_W1T);
        GEMM6_LDS(accB, Bh0, Bl0, Bh1, Bl1, smem + L_W1T);
        RELU4(accA); RELU4(accB);
        STORE_H(XA, accA);
        STORE_H(XB, accB);

        // ---- phase 2: L2 both tiles ----
        READ_A(XA, Ah0, Al0, Ah1, Al1);
        READ_A(XB, Bh0, Bl0, Bh1, Bl1);
#pragma unroll
        for (int nt = 0; nt < 4; ++nt) { accA[nt] = mk4(b2v[nt]); accB[nt] = mk4(b2v[nt]); }
        GEMM6_REG(accA, Ah0, Al0, Ah1, Al1, w2h, w2l);
        GEMM6_REG(accB, Bh0, Bl0, Bh1, Bl1, w2h, w2l);
        RELU4(accA); RELU4(accB);
        STORE_H(XA, accA);
        STORE_H(XB, accB);

        // ---- phase 3: scores both tiles ----
        READ_A(XA, Ah0, Al0, Ah1, Al1);
        READ_A(XB, Bh0, Bl0, Bh1, Bl1);
#pragma unroll
        for (int nt = 0; nt < 4; ++nt) { accA[nt] = mk4(ckreg[nt]); accB[nt] = mk4(ckreg[nt]); }
        GEMM6_LDS(accA, Ah0, Al0, Ah1, Al1, smem + L_G);
        GEMM6_LDS(accB, Bh0, Bl0, Bh1, Bl1, smem + L_G);

        // prefetch next pair PE + A-writes (planes free after the READ_As above)
        if (p == 0) {
            pe_values(vA, target_poses + ((size_t)(s * 256 + (8 + w) * 16 + l15)) * 16, g);
            writeA16(XA, l15, swz, g, vA);
            pe_values(vB, target_poses + ((size_t)(s * 256 + (12 + w) * 16 + l15)) * 16, g);
            writeA16(XB, l15, swz, g, vB);
        }

        // ---- softmax + transposed stores ----
        const int qoffA = (p * 8 + w) * 16 + q4;
        const int qoffB = (p * 8 + 4 + w) * 16 + q4;
        SOFTMAX_STORE(accA, qoffA);
        SOFTMAX_STORE(accB, qoffB);
    }
}

extern "C" void kernel_launch(void* const* d_in, const int* in_sizes, int n_in,
                              void* d_out, int out_size, void* d_ws, size_t ws_size,
                              hipStream_t stream) {
    const float* input_poses  = (const float*)d_in[0];
    const float* target_poses = (const float*)d_in[1];
    const float* W1 = (const float*)d_in[2];
    const float* b1 = (const float*)d_in[3];
    const float* W2 = (const float*)d_in[4];
    const float* b2 = (const float*)d_in[5];
    const float* W3 = (const float*)d_in[6];
    const float* b3 = (const float*)d_in[7];
    float* out = (float*)d_out;
    char* ws = (char*)d_ws;   // uses 49408 bytes

    precompute_kernel<<<dim3(8), dim3(256), 0, stream>>>(W1, b1, W2, W3, b3, ws);
    cam_mfma_kernel<<<dim3(1024), dim3(256), 0, stream>>>(
        input_poses, target_poses, b2, ws, out);
}